// Round 1
// baseline (239.783 us; speedup 1.0000x reference)
//
#include <hip/hip_runtime.h>
#include <math.h>

typedef unsigned int uint;

#define NTHREADS 256
#define KTOP 200
#define CAP 1024
#define NCLS 21   // total classes incl background (asserted from sizes host-side)

__device__ __forceinline__ uint f32_key(float f) {
  uint u = __float_as_uint(f);
  return (u & 0x80000000u) ? ~u : (u | 0x80000000u);
}

// ---------------- Kernel A: decode boxes + f64 LSE + per-class sortable keys ----
__global__ __launch_bounds__(NTHREADS) void prep_kernel(
    const float* __restrict__ bboxes,   // [B,4,N]
    const float* __restrict__ scores,   // [B,21,N]
    const float* __restrict__ dboxes,   // [N,4]
    const float* __restrict__ conf_th,  // [20]
    const float* __restrict__ scale_xy_p,
    const float* __restrict__ scale_wh_p,
    float4* __restrict__ boxes_out,     // [B*N]
    double* __restrict__ lse_out,       // [B*N]
    uint*  __restrict__ keys_out,       // [B,20,N]
    int B, int N)
{
  __shared__ double s_logth[NCLS - 1];
  if (threadIdx.x < NCLS - 1) s_logth[threadIdx.x] = log((double)conf_th[threadIdx.x]);
  __syncthreads();

  int gid = blockIdx.x * blockDim.x + threadIdx.x;
  int total = B * N;
  if (gid >= total) return;
  int b = gid / N;
  int n = gid - b * N;

  float sxy = *scale_xy_p, swh = *scale_wh_p;

  // box decode (f32, same formula as reference)
  const float* bb = bboxes + (size_t)b * 4 * N + n;
  float bx = bb[0];
  float by = bb[(size_t)N];
  float bw = bb[2 * (size_t)N];
  float bh = bb[3 * (size_t)N];
  float4 d = reinterpret_cast<const float4*>(dboxes)[n];  // cx,cy,w,h
  float x = sxy * bx * d.z + d.x;
  float y = sxy * by * d.w + d.y;
  float w = expf(swh * bw) * d.z;
  float h = expf(swh * bh) * d.w;
  boxes_out[gid] = make_float4(x - 0.5f * w, y - 0.5f * h, x + 0.5f * w, y + 0.5f * h);

  // softmax LSE in f64 (deterministic sequential sum; ordering matches true math)
  const float* sc = scores + (size_t)b * NCLS * N + n;
  float v[NCLS];
  float mx = -INFINITY;
#pragma unroll
  for (int c = 0; c < NCLS; ++c) { v[c] = sc[(size_t)c * N]; mx = fmaxf(mx, v[c]); }
  double sum = 0.0;
#pragma unroll
  for (int c = 0; c < NCLS; ++c) sum += exp((double)(v[c] - mx));
  double lse = (double)mx + log(sum);
  lse_out[gid] = lse;

  // per-class sortable key; 0 = fails conf threshold
#pragma unroll
  for (int c = 0; c < NCLS - 1; ++c) {
    double s = (double)v[c + 1] - lse;
    uint key = 0;
    if (s > s_logth[c]) key = f32_key((float)s);
    keys_out[((size_t)b * (NCLS - 1) + c) * N + n] = key;
  }
}

// ---------------- Kernel B: per (b,class) top-K select + greedy NMS ------------
__global__ __launch_bounds__(NTHREADS) void select_nms_kernel(
    const uint*  __restrict__ keys,     // [B,20,N]
    const float* __restrict__ scores,   // [B,21,N]
    const double* __restrict__ lse,     // [B*N]
    const float4* __restrict__ boxesws, // [B*N]
    const float* __restrict__ nms_th_p,
    float* __restrict__ out,            // boxes | labels | scores | keep (flat)
    int B, int N)
{
  const int C1 = NCLS - 1;
  int task = blockIdx.x;
  int b = task / C1;
  int c = task - b * C1;    // class slot 0..19 -> label c+1
  int tid = threadIdx.x;
  const uint* krow = keys + ((size_t)b * C1 + c) * N;

  __shared__ uint hist[4096];
  __shared__ double sk[CAP];
  __shared__ int si[CAP];
  __shared__ float bl[KTOP], bt[KTOP], br_[KTOP], bb_[KTOP];
  __shared__ double sarea[KTOP];
  __shared__ int alive[KTOP];
  __shared__ uint sTotal, sCnt, sL, sPrefix, sAbove, sRank;
  __shared__ int sNeedRefine;

  for (int i = tid; i < 4096; i += NTHREADS) hist[i] = 0;
  if (tid == 0) { sTotal = 0; sCnt = 0; }
  __syncthreads();

  // level-1 histogram over top 12 key bits + valid count
  uint localValid = 0;
  for (int n = tid; n < N; n += NTHREADS) {
    uint k = krow[n];
    if (k) { atomicAdd(&hist[k >> 20], 1u); localValid++; }
  }
  atomicAdd(&sTotal, localValid);
  __syncthreads();

  // per-thread partial sums of 16 bins (reuse si as scratch)
  {
    uint psum = 0;
    int base0 = tid * 16;
    for (int j = 0; j < 16; ++j) psum += hist[base0 + j];
    si[tid] = (int)psum;
  }
  __syncthreads();

  if (tid == 0) {
    uint total = sTotal;
    if (total < KTOP) {          // fewer than K pass threshold: take all valid
      sL = 1u;
      sNeedRefine = 0;
    } else {
      uint run = 0; int seg = 0;
      for (int t = 255; t >= 0; --t) {
        uint ps = (uint)si[t];
        if (run + ps >= KTOP) { seg = t; break; }
        run += ps;
      }
      uint cum = run; int bin = seg * 16;
      for (int j = seg * 16 + 15; j >= seg * 16; --j) {
        cum += hist[j];
        if (cum >= KTOP) { bin = j; break; }
      }
      uint above = cum - hist[bin];
      sL = ((uint)bin) << 20;
      if (cum <= CAP) {
        sNeedRefine = 0;
      } else {
        sNeedRefine = 1;
        sPrefix = (uint)bin;
        sAbove = above;
        sRank = KTOP - above;
      }
    }
  }
  __syncthreads();

  // refinement levels: bits [19:12], [11:4], [3:0]
  for (int lvl = 0; lvl < 3; ++lvl) {
    bool active = (sNeedRefine != 0);   // uniform
    __syncthreads();
    if (active) {
      int nbins  = (lvl == 2) ? 16 : 256;
      int shift  = (lvl == 0) ? 12 : (lvl == 1) ? 4 : 0;
      int pshift = (lvl == 0) ? 20 : (lvl == 1) ? 12 : 4;
      if (tid < nbins) hist[tid] = 0;
      __syncthreads();
      uint pref = sPrefix;
      for (int n = tid; n < N; n += NTHREADS) {
        uint k = krow[n];
        if (k && (k >> pshift) == pref) atomicAdd(&hist[(k >> shift) & (uint)(nbins - 1)], 1u);
      }
      __syncthreads();
      if (tid == 0) {
        uint above = sAbove, rank = sRank;
        uint cum = 0; int bin = 0;
        for (int j = nbins - 1; j >= 0; --j) {
          cum += hist[j];
          if (cum >= rank) { bin = j; break; }
        }
        uint cnt_ge = above + cum;
        uint newPrefix = (pref << ((lvl == 2) ? 4 : 8)) | (uint)bin;
        sPrefix = newPrefix;
        sL = newPrefix << shift;
        if (cnt_ge <= CAP || lvl == 2) {
          sNeedRefine = 0;
        } else {
          sAbove = cnt_ge - hist[bin];
          sRank = rank - (cum - hist[bin]);
        }
      }
      __syncthreads();
    }
  }
  __syncthreads();

  // collect candidates with key >= L; exact f64 score for each
  uint L = sL;
  for (int n = tid; n < N; n += NTHREADS) {
    uint k = krow[n];
    if (k >= L && k != 0) {
      uint pos = atomicAdd(&sCnt, 1u);
      if (pos < CAP) {
        si[pos] = n;
        double s = (double)scores[((size_t)b * NCLS + (c + 1)) * N + n] - lse[(size_t)b * N + n];
        sk[pos] = s;
      }
    }
  }
  __syncthreads();
  uint cnt = min(sCnt, (uint)CAP);
  for (int i = tid; i < CAP; i += NTHREADS) {
    if ((uint)i >= cnt) { sk[i] = -1e300; si[i] = 0x7FFFFFFF; }
  }
  __syncthreads();

  // bitonic sort CAP entries by (score desc, idx asc)
  for (int kk = 2; kk <= CAP; kk <<= 1) {
    for (int jj = kk >> 1; jj > 0; jj >>= 1) {
      for (int i = tid; i < CAP; i += NTHREADS) {
        int l = i ^ jj;
        if (l > i) {
          double s_i = sk[i], s_l = sk[l];
          int i_i = si[i], i_l = si[l];
          bool before_il = (s_i > s_l) || (s_i == s_l && i_i < i_l);
          bool before_li = (s_l > s_i) || (s_l == s_i && i_l < i_i);
          bool dirAsc = ((i & kk) == 0);
          bool sw = dirAsc ? before_li : before_il;
          if (sw) { sk[i] = s_l; sk[l] = s_i; si[i] = i_l; si[l] = i_i; }
        }
      }
      __syncthreads();
    }
  }

  // load top-K boxes into LDS
  int valid_cnt = (int)min(cnt, (uint)KTOP);
  if (tid < KTOP) {
    bool v = tid < valid_cnt;
    float4 bx = v ? boxesws[(size_t)b * N + si[tid]] : make_float4(0.f, 0.f, 0.f, 0.f);
    bl[tid] = bx.x; bt[tid] = bx.y; br_[tid] = bx.z; bb_[tid] = bx.w;
    double w = fmax((double)bx.z - (double)bx.x, 0.0);
    double h = fmax((double)bx.w - (double)bx.y, 0.0);
    sarea[tid] = w * h;
    alive[tid] = v ? 1 : 0;
  }

  double nth = (double)(*nms_th_p);

  // greedy NMS (f64 IoU)
  for (int i = 0; i < KTOP; ++i) {
    __syncthreads();
    if (!alive[i]) continue;              // uniform branch
    if (tid > i && tid < KTOP && alive[tid]) {
      double xx1 = fmax((double)bl[i],  (double)bl[tid]);
      double yy1 = fmax((double)bt[i],  (double)bt[tid]);
      double xx2 = fmin((double)br_[i], (double)br_[tid]);
      double yy2 = fmin((double)bb_[i], (double)bb_[tid]);
      double w = fmax(xx2 - xx1, 0.0), h = fmax(yy2 - yy1, 0.0);
      double inter = w * h;
      double iou = inter / (sarea[i] + sarea[tid] - inter + 1e-9);
      if (iou >= nth) alive[tid] = 0;
    }
  }
  __syncthreads();

  // outputs: boxes | labels | scores | keep
  size_t M = (size_t)C1 * KTOP;
  float* out_boxes  = out;
  float* out_labels = out + (size_t)B * M * 4;
  float* out_scores = out_labels + (size_t)B * M;
  float* out_keep   = out_scores + (size_t)B * M;
  if (tid < KTOP) {
    size_t slot = ((size_t)b * C1 + c) * KTOP + tid;
    bool kept = alive[tid] != 0;
    float4 bx = kept ? make_float4(bl[tid], bt[tid], br_[tid], bb_[tid])
                     : make_float4(0.f, 0.f, 0.f, 0.f);
    reinterpret_cast<float4*>(out_boxes)[slot] = bx;
    out_labels[slot] = kept ? (float)(c + 1) : 0.0f;
    out_scores[slot] = kept ? (float)exp(sk[tid]) : 0.0f;
    out_keep[slot]   = kept ? 1.0f : 0.0f;
  }
}

extern "C" void kernel_launch(void* const* d_in, const int* in_sizes, int n_in,
                              void* d_out, int out_size, void* d_ws, size_t ws_size,
                              hipStream_t stream) {
  const float* bboxes   = (const float*)d_in[0];   // [B,4,N]
  const float* scores   = (const float*)d_in[1];   // [B,21,N]
  const float* dboxes   = (const float*)d_in[2];   // [1,N,4]
  const float* conf_th  = (const float*)d_in[3];   // [20]
  const float* nms_th   = (const float*)d_in[4];   // scalar
  const float* scale_xy = (const float*)d_in[6];   // scalar
  const float* scale_wh = (const float*)d_in[7];   // scalar

  int N = in_sizes[2] / 4;
  int B = in_sizes[0] / (4 * N);
  // C assumed NCLS (=21) from in_sizes[1] / (B*N)

  // workspace layout: lse (f64) | boxes (float4) | keys (u32)
  char* ws = (char*)d_ws;
  double* lse     = (double*)ws;
  float4* boxesws = (float4*)(ws + (size_t)B * N * 8);
  uint*   keys    = (uint*)  (ws + (size_t)B * N * 8 + (size_t)B * N * 16);

  int total = B * N;
  int blocksA = (total + NTHREADS - 1) / NTHREADS;
  prep_kernel<<<blocksA, NTHREADS, 0, stream>>>(
      bboxes, scores, dboxes, conf_th, scale_xy, scale_wh,
      boxesws, lse, keys, B, N);

  select_nms_kernel<<<B * (NCLS - 1), NTHREADS, 0, stream>>>(
      keys, scores, lse, boxesws, nms_th, (float*)d_out, B, N);
}

// Round 2
// 164.873 us; speedup vs baseline: 1.4543x; 1.4543x over previous
//
#include <hip/hip_runtime.h>
#include <math.h>

typedef unsigned int uint;
typedef unsigned long long u64;

#define NTHREADS 256
#define KTOP 200
#define CAP 512
#define NCLS 21   // total classes incl background

__device__ __forceinline__ uint f32_key(float f) {
  uint u = __float_as_uint(f);
  return (u & 0x80000000u) ? ~u : (u | 0x80000000u);
}

__device__ __forceinline__ u64 flip64(double d) {
  u64 u = (u64)__double_as_longlong(d);
  return (u & 0x8000000000000000ULL) ? ~u : (u | 0x8000000000000000ULL);
}

__device__ __forceinline__ double unflip64(u64 k) {
  u64 u = (k & 0x8000000000000000ULL) ? (k ^ 0x8000000000000000ULL) : ~k;
  return __longlong_as_double((long long)u);
}

// ---------------- Kernel A: decode boxes + f64 LSE + per-class sortable keys ----
__global__ __launch_bounds__(NTHREADS) void prep_kernel(
    const float* __restrict__ bboxes,   // [B,4,N]
    const float* __restrict__ scores,   // [B,21,N]
    const float* __restrict__ dboxes,   // [N,4]
    const float* __restrict__ conf_th,  // [20]
    const float* __restrict__ scale_xy_p,
    const float* __restrict__ scale_wh_p,
    float4* __restrict__ boxes_out,     // [B*N]
    double* __restrict__ lse_out,       // [B*N]
    uint*  __restrict__ keys_out,       // [B,20,N]
    int B, int N)
{
  __shared__ double s_logth[NCLS - 1];
  if (threadIdx.x < NCLS - 1) s_logth[threadIdx.x] = log((double)conf_th[threadIdx.x]);
  __syncthreads();

  int gid = blockIdx.x * blockDim.x + threadIdx.x;
  int total = B * N;
  if (gid >= total) return;
  int b = gid / N;
  int n = gid - b * N;

  float sxy = *scale_xy_p, swh = *scale_wh_p;

  const float* bb = bboxes + (size_t)b * 4 * N + n;
  float bx = bb[0];
  float by = bb[(size_t)N];
  float bw = bb[2 * (size_t)N];
  float bh = bb[3 * (size_t)N];
  float4 d = reinterpret_cast<const float4*>(dboxes)[n];  // cx,cy,w,h
  float x = sxy * bx * d.z + d.x;
  float y = sxy * by * d.w + d.y;
  float w = expf(swh * bw) * d.z;
  float h = expf(swh * bh) * d.w;
  boxes_out[gid] = make_float4(x - 0.5f * w, y - 0.5f * h, x + 0.5f * w, y + 0.5f * h);

  const float* sc = scores + (size_t)b * NCLS * N + n;
  float v[NCLS];
  float mx = -INFINITY;
#pragma unroll
  for (int c = 0; c < NCLS; ++c) { v[c] = sc[(size_t)c * N]; mx = fmaxf(mx, v[c]); }
  double sum = 0.0;
#pragma unroll
  for (int c = 0; c < NCLS; ++c) sum += exp((double)(v[c] - mx));
  double lse = (double)mx + log(sum);
  lse_out[gid] = lse;

#pragma unroll
  for (int c = 0; c < NCLS - 1; ++c) {
    double s = (double)v[c + 1] - lse;
    uint key = 0;
    if (s > s_logth[c]) key = f32_key((float)s);
    keys_out[((size_t)b * (NCLS - 1) + c) * N + n] = key;
  }
}

// ---------------- Kernel B: per (b,class) top-K select + bitmask NMS -----------
__global__ __launch_bounds__(NTHREADS) void select_nms_kernel(
    const uint*  __restrict__ keys,     // [B,20,N]
    const float* __restrict__ scores,   // [B,21,N]
    const double* __restrict__ lse,     // [B*N]
    const float4* __restrict__ boxesws, // [B*N]
    const float* __restrict__ nms_th_p,
    float* __restrict__ out,            // boxes | labels | scores | keep (flat)
    int B, int N)
{
  const int C1 = NCLS - 1;
  int task = blockIdx.x;
  int b = task / C1;
  int c = task - b * C1;    // class slot 0..19 -> label c+1
  int tid = threadIdx.x;
  const uint* krow = keys + ((size_t)b * C1 + c) * N;
  const uint4* krow4 = reinterpret_cast<const uint4*>(krow);
  int nv = N >> 2;
  int ntail = N & 3;

  __shared__ uint hist[4096];
  __shared__ u64 skey[CAP];
  __shared__ int si[CAP];            // also scratch for per-thread psums
  __shared__ float bl[KTOP], bt[KTOP], br_[KTOP], bb_[KTOP];
  __shared__ double sarea[KTOP];
  __shared__ u64 smask[KTOP][4];
  __shared__ u64 saliveW[4];
  __shared__ uint sTotal, sCnt, sL, sPrefix, sAbove, sRank;
  __shared__ int sNeedRefine;

  for (int i = tid; i < 4096; i += NTHREADS) hist[i] = 0;
  if (tid == 0) { sTotal = 0; sCnt = 0; }
  __syncthreads();

  // ---- pass 1: histogram over top 12 key bits + valid count (uint4 loads)
  uint localValid = 0;
  for (int i = tid; i < nv; i += NTHREADS) {
    uint4 k = krow4[i];
    if (k.x) { atomicAdd(&hist[k.x >> 20], 1u); localValid++; }
    if (k.y) { atomicAdd(&hist[k.y >> 20], 1u); localValid++; }
    if (k.z) { atomicAdd(&hist[k.z >> 20], 1u); localValid++; }
    if (k.w) { atomicAdd(&hist[k.w >> 20], 1u); localValid++; }
  }
  for (int n = (N & ~3) + tid; n < N; n += NTHREADS) {
    uint k = krow[n];
    if (k) { atomicAdd(&hist[k >> 20], 1u); localValid++; }
  }
  atomicAdd(&sTotal, localValid);
  __syncthreads();

  // per-thread partial sums of 16 bins (scratch in si)
  {
    uint psum = 0;
    int base0 = tid * 16;
    for (int j = 0; j < 16; ++j) psum += hist[base0 + j];
    si[tid] = (int)psum;
  }
  __syncthreads();

  if (tid == 0) {
    uint total = sTotal;
    if (total < KTOP) {          // fewer than K pass threshold: take all valid
      sL = 1u;
      sNeedRefine = 0;
    } else {
      uint run = 0; int seg = 0;
      for (int t = 255; t >= 0; --t) {
        uint ps = (uint)si[t];
        if (run + ps >= KTOP) { seg = t; break; }
        run += ps;
      }
      uint cum = run; int bin = seg * 16;
      for (int j = seg * 16 + 15; j >= seg * 16; --j) {
        cum += hist[j];
        if (cum >= KTOP) { bin = j; break; }
      }
      uint above = cum - hist[bin];
      sL = ((uint)bin) << 20;
      if (cum <= CAP) {
        sNeedRefine = 0;
      } else {
        sNeedRefine = 1;
        sPrefix = (uint)bin;
        sAbove = above;
        sRank = KTOP - above;
      }
    }
  }
  __syncthreads();

  // ---- refinement levels: bits [19:12], [11:4], [3:0]
  for (int lvl = 0; lvl < 3; ++lvl) {
    bool active = (sNeedRefine != 0);   // uniform
    __syncthreads();
    if (active) {
      int nbins  = (lvl == 2) ? 16 : 256;
      int shift  = (lvl == 0) ? 12 : (lvl == 1) ? 4 : 0;
      int pshift = (lvl == 0) ? 20 : (lvl == 1) ? 12 : 4;
      if (tid < nbins) hist[tid] = 0;
      __syncthreads();
      uint pref = sPrefix;
      for (int i = tid; i < nv; i += NTHREADS) {
        uint4 kv = krow4[i];
        if (kv.x && (kv.x >> pshift) == pref) atomicAdd(&hist[(kv.x >> shift) & (uint)(nbins - 1)], 1u);
        if (kv.y && (kv.y >> pshift) == pref) atomicAdd(&hist[(kv.y >> shift) & (uint)(nbins - 1)], 1u);
        if (kv.z && (kv.z >> pshift) == pref) atomicAdd(&hist[(kv.z >> shift) & (uint)(nbins - 1)], 1u);
        if (kv.w && (kv.w >> pshift) == pref) atomicAdd(&hist[(kv.w >> shift) & (uint)(nbins - 1)], 1u);
      }
      for (int n = (N & ~3) + tid; n < N; n += NTHREADS) {
        uint k = krow[n];
        if (k && (k >> pshift) == pref) atomicAdd(&hist[(k >> shift) & (uint)(nbins - 1)], 1u);
      }
      __syncthreads();
      if (tid == 0) {
        uint above = sAbove, rank = sRank;
        uint cum = 0; int bin = 0;
        for (int j = nbins - 1; j >= 0; --j) {
          cum += hist[j];
          if (cum >= rank) { bin = j; break; }
        }
        uint cnt_ge = above + cum;
        uint newPrefix = (pref << ((lvl == 2) ? 4 : 8)) | (uint)bin;
        sPrefix = newPrefix;
        sL = newPrefix << shift;
        if (cnt_ge <= CAP || lvl == 2) {
          sNeedRefine = 0;
        } else {
          sAbove = cnt_ge - hist[bin];
          sRank = rank - (cum - hist[bin]);
        }
      }
      __syncthreads();
    }
  }
  __syncthreads();

  // ---- collect candidate indices with key >= L (uint4)
  uint L = sL;
  for (int i = tid; i < nv; i += NTHREADS) {
    uint4 kv = krow4[i];
    int base = i << 2;
    if (kv.x >= L) { uint p = atomicAdd(&sCnt, 1u); if (p < CAP) si[p] = base; }
    if (kv.y >= L) { uint p = atomicAdd(&sCnt, 1u); if (p < CAP) si[p] = base + 1; }
    if (kv.z >= L) { uint p = atomicAdd(&sCnt, 1u); if (p < CAP) si[p] = base + 2; }
    if (kv.w >= L) { uint p = atomicAdd(&sCnt, 1u); if (p < CAP) si[p] = base + 3; }
  }
  for (int n = (N & ~3) + tid; n < N; n += NTHREADS) {
    uint k = krow[n];
    if (k >= L) { uint p = atomicAdd(&sCnt, 1u); if (p < CAP) si[p] = n; }
  }
  __syncthreads();
  uint cnt = min(sCnt, (uint)CAP);

  // gather exact f64 scores -> packed sortable keys; pad rest
  for (int p = tid; p < CAP; p += NTHREADS) {
    if ((uint)p < cnt) {
      int n = si[p];
      double s = (double)scores[((size_t)b * NCLS + (c + 1)) * N + n] - lse[(size_t)b * N + n];
      skey[p] = flip64(s);
    } else {
      skey[p] = 0ULL;
      si[p] = 0x7FFFFFFF;
    }
  }
  __syncthreads();

  // ---- bitonic sort CAP=512 entries by (key desc, idx asc)
  for (int kk = 2; kk <= CAP; kk <<= 1) {
    for (int jj = kk >> 1; jj > 0; jj >>= 1) {
      for (int i = tid; i < CAP; i += NTHREADS) {
        int l = i ^ jj;
        if (l > i) {
          u64 k_i = skey[i], k_l = skey[l];
          int i_i = si[i], i_l = si[l];
          bool before_il = (k_i > k_l) || (k_i == k_l && i_i < i_l);
          bool dirAsc = ((i & kk) == 0);
          bool sw = dirAsc ? !before_il : before_il;
          if (sw) { skey[i] = k_l; skey[l] = k_i; si[i] = i_l; si[l] = i_i; }
        }
      }
      __syncthreads();
    }
  }

  int valid_cnt = (int)min(cnt, (uint)KTOP);

  // ---- load top-K boxes into LDS
  if (tid < KTOP) {
    bool v = tid < valid_cnt;
    float4 bx = v ? boxesws[(size_t)b * N + si[tid]] : make_float4(0.f, 0.f, 0.f, 0.f);
    bl[tid] = bx.x; bt[tid] = bx.y; br_[tid] = bx.z; bb_[tid] = bx.w;
    double w = fmax((double)bx.z - (double)bx.x, 0.0);
    double h = fmax((double)bx.w - (double)bx.y, 0.0);
    sarea[tid] = w * h;
  }
  __syncthreads();

  double nth = (double)(*nms_th_p);

  // ---- build 200x200 suppression bitmask fully in parallel
  for (int u = tid; u < KTOP * 4; u += NTHREADS) {
    int i = u >> 2, w = u & 3;
    u64 m = 0;
    if (i < valid_cnt) {
      int j0 = max(i + 1, w * 64);
      int j1 = min(valid_cnt, w * 64 + 64);
      double li = (double)bl[i], ti = (double)bt[i];
      double ri = (double)br_[i], bi = (double)bb_[i];
      double ai = sarea[i];
      for (int j = j0; j < j1; ++j) {
        double xx1 = fmax(li, (double)bl[j]);
        double yy1 = fmax(ti, (double)bt[j]);
        double xx2 = fmin(ri, (double)br_[j]);
        double yy2 = fmin(bi, (double)bb_[j]);
        double ww = fmax(xx2 - xx1, 0.0), hh = fmax(yy2 - yy1, 0.0);
        double inter = ww * hh;
        double iou = inter / (ai + sarea[j] - inter + 1e-9);
        if (iou >= nth) m |= 1ULL << (j - w * 64);
      }
    }
    smask[i][w] = m;
  }
  __syncthreads();

  // ---- greedy resolve: single wave, no barriers
  if (tid < 64) {
    u64 aw = 0;
    if (tid < 4) {
      int lo = tid * 64;
      int nb = valid_cnt - lo;
      nb = nb < 0 ? 0 : (nb > 64 ? 64 : nb);
      aw = (nb == 64) ? ~0ULL : ((nb > 0) ? ((1ULL << nb) - 1ULL) : 0ULL);
    }
    for (int i = 0; i < valid_cnt; ++i) {
      u64 wa = __shfl(aw, i >> 6);
      if ((wa >> (i & 63)) & 1ULL) {
        if (tid < 4) aw &= ~smask[i][tid];
      }
    }
    if (tid < 4) saliveW[tid] = aw;
  }
  __syncthreads();

  // ---- outputs: boxes | labels | scores | keep
  size_t M = (size_t)C1 * KTOP;
  float* out_boxes  = out;
  float* out_labels = out + (size_t)B * M * 4;
  float* out_scores = out_labels + (size_t)B * M;
  float* out_keep   = out_scores + (size_t)B * M;
  if (tid < KTOP) {
    size_t slot = ((size_t)b * C1 + c) * KTOP + tid;
    bool kept = (tid < valid_cnt) && ((saliveW[tid >> 6] >> (tid & 63)) & 1ULL);
    float4 bx = kept ? make_float4(bl[tid], bt[tid], br_[tid], bb_[tid])
                     : make_float4(0.f, 0.f, 0.f, 0.f);
    reinterpret_cast<float4*>(out_boxes)[slot] = bx;
    out_labels[slot] = kept ? (float)(c + 1) : 0.0f;
    out_scores[slot] = kept ? (float)exp(unflip64(skey[tid])) : 0.0f;
    out_keep[slot]   = kept ? 1.0f : 0.0f;
  }
}

extern "C" void kernel_launch(void* const* d_in, const int* in_sizes, int n_in,
                              void* d_out, int out_size, void* d_ws, size_t ws_size,
                              hipStream_t stream) {
  const float* bboxes   = (const float*)d_in[0];   // [B,4,N]
  const float* scores   = (const float*)d_in[1];   // [B,21,N]
  const float* dboxes   = (const float*)d_in[2];   // [1,N,4]
  const float* conf_th  = (const float*)d_in[3];   // [20]
  const float* nms_th   = (const float*)d_in[4];   // scalar
  const float* scale_xy = (const float*)d_in[6];   // scalar
  const float* scale_wh = (const float*)d_in[7];   // scalar

  int N = in_sizes[2] / 4;
  int B = in_sizes[0] / (4 * N);

  // workspace layout: lse (f64) | boxes (float4) | keys (u32)
  char* ws = (char*)d_ws;
  double* lse     = (double*)ws;
  float4* boxesws = (float4*)(ws + (size_t)B * N * 8);
  uint*   keys    = (uint*)  (ws + (size_t)B * N * 8 + (size_t)B * N * 16);

  int total = B * N;
  int blocksA = (total + NTHREADS - 1) / NTHREADS;
  prep_kernel<<<blocksA, NTHREADS, 0, stream>>>(
      bboxes, scores, dboxes, conf_th, scale_xy, scale_wh,
      boxesws, lse, keys, B, N);

  select_nms_kernel<<<B * (NCLS - 1), NTHREADS, 0, stream>>>(
      keys, scores, lse, boxesws, nms_th, (float*)d_out, B, N);
}